// Round 3
// baseline (707.009 us; speedup 1.0000x reference)
//
#include <hip/hip_runtime.h>
#include <hip/hip_fp16.h>

// R3: pipelined global_load_lds staging, [slot][row] conflict-free LDS,
// 128-token tiles (halve weight re-fetch), reg-prefetched weights.

#define T_TOK 1024
#define H_DIM 2048
#define I_DIM 1408
#define E_NUM 32
#define ISH   2816

typedef _Float16 f16_t;
typedef f16_t f16x8 __attribute__((ext_vector_type(8)));
typedef float f32x16 __attribute__((ext_vector_type(16)));

__device__ __forceinline__ uint32_t h2_u32(__half2 h){union{__half2 h;uint32_t u;}c;c.h=h;return c.u;}
__device__ __forceinline__ __half2 u32_h2(uint32_t u){union{uint32_t u;__half2 h;}c;c.u=u;return c.h;}

__device__ __forceinline__ void glds16(const void* g, void* l) {
    __builtin_amdgcn_global_load_lds((const __attribute__((address_space(1))) void*)g,
                                     (__attribute__((address_space(3))) void*)l, 16, 0, 0);
}

// codes pair -> f16x2 of (c-z)*s  (exact: 1024+c constructed into mantissa)
__device__ __forceinline__ uint32_t unpack_pair(uint32_t t, uint32_t z2, uint32_t s2) {
    uint32_t m = 0x64006400u | (t & 0xFu) | ((t & 0xF0u) << 12);
    __half2 h = __hsub2(u32_h2(m), u32_h2(z2));
    h = __hmul2(h, u32_h2(s2));
    return h2_u32(h);
}
__device__ __forceinline__ f16x8 unpack_frag(uint32_t w, uint32_t z2, uint32_t s2) {
    union { uint32_t u[4]; f16x8 v; } r;
    r.u[0] = unpack_pair(w, z2, s2);
    r.u[1] = unpack_pair(w >> 8, z2, s2);
    r.u[2] = unpack_pair(w >> 16, z2, s2);
    r.u[3] = unpack_pair(w >> 24, z2, s2);
    return r.v;
}
// raw slot s holds x-chunk u = inv_perm(s) (matches int4 word order {4c..4c+3, 8+4c..})
__device__ __forceinline__ int invp(int s) { return ((s >> 1) & 3) | ((s & 1) << 2) | (s & 8); }

__device__ __forceinline__ float sigmoidf_(float v) { return 1.f / (1.f + __expf(-v)); }

// ---------------- prep: x f32 -> f16 ----------------
__global__ __launch_bounds__(256)
void k_cvt(const float* __restrict__ in, __half* __restrict__ outp)
{
    const int i = blockIdx.x * 256 + threadIdx.x;
    const float4 a = *(const float4*)(in + (size_t)i * 8);
    const float4 b = *(const float4*)(in + (size_t)i * 8 + 4);
    int4 o;
    o.x = h2_u32(__floats2half2_rn(a.x, a.y));
    o.y = h2_u32(__floats2half2_rn(a.z, a.w));
    o.z = h2_u32(__floats2half2_rn(b.x, b.y));
    o.w = h2_u32(__floats2half2_rn(b.z, b.w));
    *(int4*)(outp + (size_t)i * 8) = o;
}

// ---------------- prep: transpose f32 [R][C] -> f16 [C][R] ----------------
__global__ __launch_bounds__(256)
void k_tr(const float* __restrict__ in, __half* __restrict__ outp, int R, int C)
{
    __shared__ float tile[32][33];
    const int tx = threadIdx.x & 31, ty = threadIdx.x >> 5;
    const int cx = blockIdx.x * 32 + tx;
    #pragma unroll
    for (int j = 0; j < 4; ++j)
        tile[ty + j * 8][tx] = in[(size_t)(blockIdx.y * 32 + ty + j * 8) * C + cx];
    __syncthreads();
    const int ox = blockIdx.y * 32 + tx;
    #pragma unroll
    for (int j = 0; j < 4; ++j)
        outp[(size_t)(blockIdx.x * 32 + ty + j * 8) * R + ox] = __float2half(tile[tx][ty + j * 8]);
}

// ---------------- router ----------------
__global__ __launch_bounds__(256)
void k_router(const float* __restrict__ x, const float* __restrict__ gw,
              int* __restrict__ counts, int* __restrict__ elist, float* __restrict__ ecoef)
{
    const int t = blockIdx.x;
    const int tid = threadIdx.x;
    const int e = tid & 31, seg = tid >> 5;
    const float* xr = x + (size_t)t * H_DIM;
    float p = 0.f;
    for (int k = 0; k < 256; ++k)
        p = fmaf(xr[seg * 256 + k], gw[(seg * 256 + k) * E_NUM + e], p);
    __shared__ float ps[8][32];
    __shared__ float sc[32];
    ps[seg][e] = p;
    __syncthreads();
    if (tid < 32) {
        float s = 0.f;
        #pragma unroll
        for (int g = 0; g < 8; ++g) s += ps[g][tid];
        sc[tid] = sigmoidf_(s);
    }
    __syncthreads();
    if (tid == 0) {
        unsigned used = 0; float ssum = 0.f;
        int sel[4]; float sv[4];
        for (int k = 0; k < 4; ++k) {
            float best = -1.f; int bi = 0;
            for (int e2 = 0; e2 < 32; ++e2) {
                if (used & (1u << e2)) continue;
                if (sc[e2] > best) { best = sc[e2]; bi = e2; }
            }
            used |= 1u << bi; sel[k] = bi; sv[k] = best; ssum += best;
        }
        const float inv = 2.5f / (ssum + 1e-20f);
        for (int k = 0; k < 4; ++k) {
            const int ee = sel[k];
            const int pos = atomicAdd(&counts[ee], 1);
            elist[ee * T_TOK + pos] = t | (k << 20);
            ecoef[ee * T_TOK + pos] = sv[k] * inv;
        }
    }
}

// ================= routed gate/up: 128 tok x 128 i, 512 thr =================
struct GUW { int4 g1, g2, u1, u2; int gz, uz; float gs, us; };
__device__ __forceinline__ GUW gu_wload(const int* gwr, const int* uwr, const int* gzr,
                                        const int* uzr, const float* gsr, const float* usr,
                                        int g, int c) {
    GUW w;
    w.g1 = *(const int4*)(gwr + g * 16 + 4 * c);
    w.g2 = *(const int4*)(gwr + g * 16 + 8 + 4 * c);
    w.u1 = *(const int4*)(uwr + g * 16 + 4 * c);
    w.u2 = *(const int4*)(uwr + g * 16 + 8 + 4 * c);
    w.gz = gzr[g]; w.uz = uzr[g]; w.gs = gsr[g]; w.us = usr[g];
    return w;
}

__global__ __launch_bounds__(512)
void k_gateup(const __half* __restrict__ xq,
              const int* __restrict__ gqw, const int* __restrict__ gqz, const float* __restrict__ gsc,
              const int* __restrict__ uqw, const int* __restrict__ uqz, const float* __restrict__ usc,
              const int* __restrict__ counts, const int* __restrict__ elist, const float* __restrict__ ecoef,
              const __half* __restrict__ zrow, __half* __restrict__ h_buf)
{
    const int e = blockIdx.z;
    const int ne = counts[e];
    const int t0 = blockIdx.y * 128;
    if (t0 >= ne) return;
    const int tid = threadIdx.x;
    const int lane = tid & 63;
    const int wv = tid >> 6;
    const int li = lane & 31;
    const int c = lane >> 5;
    const int ng = wv & 3, th = wv >> 2;
    const int i_col = blockIdx.x * 128 + ng * 32 + li;

    __shared__ int toks[128];
    __shared__ float cofs[128];
    __shared__ __align__(16) char xs[2][16 * 2048];   // [buf][slot][128 rows x 16B]

    if (tid < 128) {
        const bool v = (t0 + tid) < ne;
        toks[tid] = v ? elist[e * T_TOK + t0 + tid] : -1;
        cofs[tid] = v ? ecoef[e * T_TOK + t0 + tid] : 0.f;
    }
    __syncthreads();

    const int tk0 = toks[lane], tk1 = toks[64 + lane];
    const __half* sr0 = (tk0 >= 0) ? xq + (size_t)(tk0 & 0xFFFFF) * H_DIM : zrow;
    const __half* sr1 = (tk1 >= 0) ? xq + (size_t)(tk1 & 0xFFFFF) * H_DIM : zrow;
    const int s0 = wv * 2, s1 = wv * 2 + 1;
    const int u0 = invp(s0), u1 = invp(s1);

    const size_t wrow = (size_t)(e * I_DIM + i_col);
    const int* gwr = gqw + wrow * 256;
    const int* uwr = uqw + wrow * 256;
    const int* gzr = gqz + wrow * 16;
    const int* uzr = uqz + wrow * 16;
    const float* gsr = gsc + wrow * 16;
    const float* usr = usc + wrow * 16;

    f32x16 ag0, ag1, au0, au1;
    #pragma unroll
    for (int i = 0; i < 16; ++i) { ag0[i] = 0.f; ag1[i] = 0.f; au0[i] = 0.f; au1[i] = 0.f; }

#define GU_STAGE(B, g) do { \
    glds16(sr0 + (g) * 128 + u0 * 8, xs[B] + s0 * 2048); \
    glds16(sr1 + (g) * 128 + u0 * 8, xs[B] + s0 * 2048 + 1024); \
    glds16(sr0 + (g) * 128 + u1 * 8, xs[B] + s1 * 2048); \
    glds16(sr1 + (g) * 128 + u1 * 8, xs[B] + s1 * 2048 + 1024); } while (0)

#define GU_COMP(B, W) do { \
    const uint32_t gz2 = 0x64006400u | ((uint32_t)(W).gz * 0x10001u); \
    const uint32_t uz2 = 0x64006400u | ((uint32_t)(W).uz * 0x10001u); \
    const uint32_t gs2 = h2_u32(__float2half2_rn((W).gs)); \
    const uint32_t us2 = h2_u32(__float2half2_rn((W).us)); \
    const uint32_t gw8[8] = {(uint32_t)(W).g1.x,(uint32_t)(W).g1.y,(uint32_t)(W).g1.z,(uint32_t)(W).g1.w, \
                             (uint32_t)(W).g2.x,(uint32_t)(W).g2.y,(uint32_t)(W).g2.z,(uint32_t)(W).g2.w}; \
    const uint32_t uw8[8] = {(uint32_t)(W).u1.x,(uint32_t)(W).u1.y,(uint32_t)(W).u1.z,(uint32_t)(W).u1.w, \
                             (uint32_t)(W).u2.x,(uint32_t)(W).u2.y,(uint32_t)(W).u2.z,(uint32_t)(W).u2.w}; \
    _Pragma("unroll") \
    for (int m = 0; m < 8; ++m) { \
        const f16x8 bg = unpack_frag(gw8[m], gz2, gs2); \
        const f16x8 bu = unpack_frag(uw8[m], uz2, us2); \
        const char* ap = xs[B] + (2 * m + c) * 2048 + (th * 64 + li) * 16; \
        const f16x8 a0 = *(const f16x8*)ap; \
        const f16x8 a1 = *(const f16x8*)(ap + 512); \
        ag0 = __builtin_amdgcn_mfma_f32_32x32x16_f16(a0, bg, ag0, 0, 0, 0); \
        au0 = __builtin_amdgcn_mfma_f32_32x32x16_f16(a0, bu, au0, 0, 0, 0); \
        ag1 = __builtin_amdgcn_mfma_f32_32x32x16_f16(a1, bg, ag1, 0, 0, 0); \
        au1 = __builtin_amdgcn_mfma_f32_32x32x16_f16(a1, bu, au1, 0, 0, 0); \
    } } while (0)

    GUW W0 = gu_wload(gwr, uwr, gzr, uzr, gsr, usr, 0, c), W1;
    GU_STAGE(0, 0);
    __syncthreads();
    for (int g = 0; g < 16; g += 2) {
        GU_STAGE(1, g + 1);
        W1 = gu_wload(gwr, uwr, gzr, uzr, gsr, usr, g + 1, c);
        GU_COMP(0, W0);
        __syncthreads();
        if (g + 2 < 16) {
            GU_STAGE(0, g + 2);
            W0 = gu_wload(gwr, uwr, gzr, uzr, gsr, usr, g + 2, c);
        }
        GU_COMP(1, W1);
        __syncthreads();
    }

    #pragma unroll
    for (int r = 0; r < 16; ++r) {
        const int row0 = (r & 3) + 8 * (r >> 2) + 4 * c;
        {
            const int rr = th * 64 + row0;
            const int tk = toks[rr];
            if (tk >= 0) {
                const float gv = ag0[r], uv = au0[r];
                h_buf[(size_t)((tk & 0xFFFFF) * 4 + (tk >> 20)) * I_DIM + i_col] =
                    __float2half(gv * sigmoidf_(gv) * uv * cofs[rr]);
            }
        }
        {
            const int rr = th * 64 + 32 + row0;
            const int tk = toks[rr];
            if (tk >= 0) {
                const float gv = ag1[r], uv = au1[r];
                h_buf[(size_t)((tk & 0xFFFFF) * 4 + (tk >> 20)) * I_DIM + i_col] =
                    __float2half(gv * sigmoidf_(gv) * uv * cofs[rr]);
            }
        }
    }
#undef GU_STAGE
#undef GU_COMP
}

// ================= routed down: 128 slot-rows x 128 h, 512 thr =================
struct DW { int4 w1, w2; int z; float s; };
__device__ __forceinline__ DW d_wload(const int* dwr, const int* dzr, const float* dsr, int g, int c) {
    DW w;
    w.w1 = *(const int4*)(dwr + g * 16 + 4 * c);
    w.w2 = *(const int4*)(dwr + g * 16 + 8 + 4 * c);
    w.z = dzr[g]; w.s = dsr[g];
    return w;
}

__global__ __launch_bounds__(512)
void k_down(const __half* __restrict__ h_buf,
            const int* __restrict__ dqw, const int* __restrict__ dqz, const float* __restrict__ dsc,
            const int* __restrict__ counts, const int* __restrict__ elist,
            const __half* __restrict__ zrow, float* __restrict__ out)
{
    const int e = blockIdx.z;
    const int ne = counts[e];
    const int t0 = blockIdx.y * 128;
    if (t0 >= ne) return;
    const int tid = threadIdx.x;
    const int lane = tid & 63;
    const int wv = tid >> 6;
    const int li = lane & 31;
    const int c = lane >> 5;
    const int ng = wv & 3, th = wv >> 2;
    const int h_col = blockIdx.x * 128 + ng * 32 + li;

    __shared__ int toks[128];
    __shared__ __align__(16) char xs[2][16 * 2048];

    if (tid < 128)
        toks[tid] = ((t0 + tid) < ne) ? elist[e * T_TOK + t0 + tid] : -1;
    __syncthreads();

    const int tk0 = toks[lane], tk1 = toks[64 + lane];
    const __half* sr0 = (tk0 >= 0) ? h_buf + (size_t)((tk0 & 0xFFFFF) * 4 + (tk0 >> 20)) * I_DIM : zrow;
    const __half* sr1 = (tk1 >= 0) ? h_buf + (size_t)((tk1 & 0xFFFFF) * 4 + (tk1 >> 20)) * I_DIM : zrow;
    const int s0 = wv * 2, s1 = wv * 2 + 1;
    const int u0 = invp(s0), u1 = invp(s1);

    const size_t wrow = (size_t)(e * H_DIM + h_col);
    const int* dwr = dqw + wrow * 176;
    const int* dzr = dqz + wrow * 11;
    const float* dsr = dsc + wrow * 11;

    f32x16 a0, a1;
    #pragma unroll
    for (int i = 0; i < 16; ++i) { a0[i] = 0.f; a1[i] = 0.f; }

#define D_STAGE(B, g) do { \
    glds16(sr0 + (g) * 128 + u0 * 8, xs[B] + s0 * 2048); \
    glds16(sr1 + (g) * 128 + u0 * 8, xs[B] + s0 * 2048 + 1024); \
    glds16(sr0 + (g) * 128 + u1 * 8, xs[B] + s1 * 2048); \
    glds16(sr1 + (g) * 128 + u1 * 8, xs[B] + s1 * 2048 + 1024); } while (0)

#define D_COMP(B, W) do { \
    const uint32_t z2 = 0x64006400u | ((uint32_t)(W).z * 0x10001u); \
    const uint32_t s2 = h2_u32(__float2half2_rn((W).s)); \
    const uint32_t w8[8] = {(uint32_t)(W).w1.x,(uint32_t)(W).w1.y,(uint32_t)(W).w1.z,(uint32_t)(W).w1.w, \
                            (uint32_t)(W).w2.x,(uint32_t)(W).w2.y,(uint32_t)(W).w2.z,(uint32_t)(W).w2.w}; \
    _Pragma("unroll") \
    for (int m = 0; m < 8; ++m) { \
        const f16x8 b = unpack_frag(w8[m], z2, s2); \
        const char* ap = xs[B] + (2 * m + c) * 2048 + (th * 64 + li) * 16; \
        const f16x8 x0 = *(const f16x8*)ap; \
        const f16x8 x1 = *(const f16x8*)(ap + 512); \
        a0 = __builtin_amdgcn_mfma_f32_32x32x16_f16(x0, b, a0, 0, 0, 0); \
        a1 = __builtin_amdgcn_mfma_f32_32x32x16_f16(x1, b, a1, 0, 0, 0); \
    } } while (0)

    DW W0 = d_wload(dwr, dzr, dsr, 0, c), W1;
    D_STAGE(0, 0);
    __syncthreads();
    for (int g = 0; g < 11; g += 2) {
        if (g + 1 < 11) {
            D_STAGE(1, g + 1);
            W1 = d_wload(dwr, dzr, dsr, g + 1, c);
        }
        D_COMP(0, W0);
        __syncthreads();
        if (g + 1 < 11) {
            if (g + 2 < 11) {
                D_STAGE(0, g + 2);
                W0 = d_wload(dwr, dzr, dsr, g + 2, c);
            }
            D_COMP(1, W1);
            __syncthreads();
        }
    }

    #pragma unroll
    for (int r = 0; r < 16; ++r) {
        const int row0 = (r & 3) + 8 * (r >> 2) + 4 * c;
        {
            const int tk = toks[th * 64 + row0];
            if (tk >= 0) atomicAdd(out + (size_t)(tk & 0xFFFFF) * H_DIM + h_col, a0[r]);
        }
        {
            const int tk = toks[th * 64 + 32 + row0];
            if (tk >= 0) atomicAdd(out + (size_t)(tk & 0xFFFFF) * H_DIM + h_col, a1[r]);
        }
    }
#undef D_STAGE
#undef D_COMP
}

// ================= shared gate/up: 128 tok x 128 n, 64-k chunks =================
__global__ __launch_bounds__(512)
void k_shared_gu(const __half* __restrict__ xq, const __half* __restrict__ wgt,
                 const __half* __restrict__ wut, __half* __restrict__ hs)
{
    const int t0 = blockIdx.y * 128;
    const int nb = blockIdx.x * 128;
    const int tid = threadIdx.x;
    const int lane = tid & 63;
    const int wv = tid >> 6;
    const int li = lane & 31;
    const int c = lane >> 5;
    const int ng = wv & 3, th = wv >> 2;
    const int ncol = nb + ng * 32 + li;

    __shared__ __align__(16) char xa[2][8 * 2048];   // A: 8 slots x 128 rows x 16B
    __shared__ __align__(16) char bg[2][8 * 2048];   // B gate
    __shared__ __align__(16) char bu[2][8 * 2048];   // B up

    const __half* ar0 = xq + (size_t)(t0 + lane) * H_DIM;
    const __half* ar1 = xq + (size_t)(t0 + 64 + lane) * H_DIM;
    const __half* gr0 = wgt + (size_t)(nb + lane) * H_DIM;
    const __half* gr1 = wgt + (size_t)(nb + 64 + lane) * H_DIM;
    const __half* ur0 = wut + (size_t)(nb + lane) * H_DIM;
    const __half* ur1 = wut + (size_t)(nb + 64 + lane) * H_DIM;

    f32x16 ag0, ag1, au0, au1;
    #pragma unroll
    for (int i = 0; i < 16; ++i) { ag0[i] = 0.f; ag1[i] = 0.f; au0[i] = 0.f; au1[i] = 0.f; }

#define SG_STAGE(B, g) do { \
    const int off = (g) * 64 + wv * 8; \
    glds16(ar0 + off, xa[B] + wv * 2048); \
    glds16(ar1 + off, xa[B] + wv * 2048 + 1024); \
    glds16(gr0 + off, bg[B] + wv * 2048); \
    glds16(gr1 + off, bg[B] + wv * 2048 + 1024); \
    glds16(ur0 + off, bu[B] + wv * 2048); \
    glds16(ur1 + off, bu[B] + wv * 2048 + 1024); } while (0)

#define SG_COMP(B) do { \
    _Pragma("unroll") \
    for (int m = 0; m < 4; ++m) { \
        const int so = (2 * m + c) * 2048; \
        const char* ap = xa[B] + so + (th * 64 + li) * 16; \
        const f16x8 a0 = *(const f16x8*)ap; \
        const f16x8 a1 = *(const f16x8*)(ap + 512); \
        const f16x8 wg = *(const f16x8*)(bg[B] + so + (ng * 32 + li) * 16); \
        const f16x8 wu = *(const f16x8*)(bu[B] + so + (ng * 32 + li) * 16); \
        ag0 = __builtin_amdgcn_mfma_f32_32x32x16_f16(a0, wg, ag0, 0, 0, 0); \
        au0 = __builtin_amdgcn_mfma_f32_32x32x16_f16(a0, wu, au0, 0, 0, 0); \
        ag1 = __builtin_amdgcn_mfma_f32_32x32x16_f16(a1, wg, ag1, 0, 0, 0); \
        au1 = __builtin_amdgcn_mfma_f32_32x32x16_f16(a1, wu, au1, 0, 0, 0); \
    } } while (0)

    SG_STAGE(0, 0);
    __syncthreads();
    for (int g = 0; g < 32; g += 2) {
        SG_STAGE(1, g + 1);
        SG_COMP(0);
        __syncthreads();
        if (g + 2 < 32) SG_STAGE(0, g + 2);
        SG_COMP(1);
        __syncthreads();
    }

    #pragma unroll
    for (int r = 0; r < 16; ++r) {
        const int row0 = (r & 3) + 8 * (r >> 2) + 4 * c;
        {
            const float gv = ag0[r], uv = au0[r];
            hs[(size_t)(t0 + th * 64 + row0) * ISH + ncol] = __float2half(gv * sigmoidf_(gv) * uv);
        }
        {
            const float gv = ag1[r], uv = au1[r];
            hs[(size_t)(t0 + th * 64 + 32 + row0) * ISH + ncol] = __float2half(gv * sigmoidf_(gv) * uv);
        }
    }
#undef SG_STAGE
#undef SG_COMP
}

// ================= shared down: 128 tok x 128 h, 64-k chunks =================
__global__ __launch_bounds__(512)
void k_shared_down(const __half* __restrict__ hs, const __half* __restrict__ wdt,
                   float* __restrict__ out)
{
    const int t0 = blockIdx.y * 128;
    const int hb = blockIdx.x * 128;
    const int tid = threadIdx.x;
    const int lane = tid & 63;
    const int wv = tid >> 6;
    const int li = lane & 31;
    const int c = lane >> 5;
    const int ng = wv & 3, th = wv >> 2;
    const int hcol = hb + ng * 32 + li;

    __shared__ __align__(16) char xa[2][8 * 2048];
    __shared__ __align__(16) char bd[2][8 * 2048];

    const __half* ar0 = hs + (size_t)(t0 + lane) * ISH;
    const __half* ar1 = hs + (size_t)(t0 + 64 + lane) * ISH;
    const __half* dr0 = wdt + (size_t)(hb + lane) * ISH;
    const __half* dr1 = wdt + (size_t)(hb + 64 + lane) * ISH;

    f32x16 a0, a1;
    #pragma unroll
    for (int i = 0; i < 16; ++i) { a0[i] = 0.f; a1[i] = 0.f; }

#define SD_STAGE(B, g) do { \
    const int off = (g) * 64 + wv * 8; \
    glds16(ar0 + off, xa[B] + wv * 2048); \
    glds16(ar1 + off, xa[B] + wv * 2048 + 1024); \
    glds16(dr0 + off, bd[B] + wv * 2048); \
    glds16(dr1 + off, bd[B] + wv * 2048 + 1024); } while (0)

#define SD_COMP(B) do { \
    _Pragma("unroll") \
    for (int m = 0; m < 4; ++m) { \
        const int so = (2 * m + c) * 2048; \
        const char* ap = xa[B] + so + (th * 64 + li) * 16; \
        const f16x8 x0 = *(const f16x8*)ap; \
        const f16x8 x1 = *(const f16x8*)(ap + 512); \
        const f16x8 wd = *(const f16x8*)(bd[B] + so + (ng * 32 + li) * 16); \
        a0 = __builtin_amdgcn_mfma_f32_32x32x16_f16(x0, wd, a0, 0, 0, 0); \
        a1 = __builtin_amdgcn_mfma_f32_32x32x16_f16(x1, wd, a1, 0, 0, 0); \
    } } while (0)

    SD_STAGE(0, 0);
    __syncthreads();
    for (int g = 0; g < 44; g += 2) {
        SD_STAGE(1, g + 1);
        SD_COMP(0);
        __syncthreads();
        if (g + 2 < 44) SD_STAGE(0, g + 2);
        SD_COMP(1);
        __syncthreads();
    }

    #pragma unroll
    for (int r = 0; r < 16; ++r) {
        const int row0 = (r & 3) + 8 * (r >> 2) + 4 * c;
        out[(size_t)(t0 + th * 64 + row0) * H_DIM + hcol] = a0[r];
        out[(size_t)(t0 + th * 64 + 32 + row0) * H_DIM + hcol] = a1[r];
    }
#undef SD_STAGE
#undef SD_COMP
}

extern "C" void kernel_launch(void* const* d_in, const int* in_sizes, int n_in,
                              void* d_out, int out_size, void* d_ws, size_t ws_size,
                              hipStream_t stream)
{
    const float* x   = (const float*)d_in[0];
    const float* gw  = (const float*)d_in[1];
    const int*   gqw = (const int*)d_in[2];
    const int*   gqz = (const int*)d_in[3];
    const float* gsc = (const float*)d_in[4];
    const int*   uqw = (const int*)d_in[5];
    const int*   uqz = (const int*)d_in[6];
    const float* usc = (const float*)d_in[7];
    const int*   dqw = (const int*)d_in[8];
    const int*   dqz = (const int*)d_in[9];
    const float* dsc = (const float*)d_in[10];
    const float* sgw = (const float*)d_in[11];
    const float* suw = (const float*)d_in[12];
    const float* sdw = (const float*)d_in[13];
    float* out = (float*)d_out;

    char* ws = (char*)d_ws;
    constexpr size_t OFF_COUNTS = 0;                                   // 1KB (counts)
    constexpr size_t OFF_ZERO   = 1024;                                // 8KB zeros
    constexpr size_t OFF_ELIST  = OFF_ZERO + 8192;
    constexpr size_t OFF_ECOEF  = OFF_ELIST + (size_t)E_NUM * T_TOK * 4;
    constexpr size_t OFF_XQ     = OFF_ECOEF + (size_t)E_NUM * T_TOK * 4;
    constexpr size_t OFF_WGT    = OFF_XQ + (size_t)T_TOK * H_DIM * 2;
    constexpr size_t OFF_WUT    = OFF_WGT + (size_t)ISH * H_DIM * 2;
    constexpr size_t OFF_WDT    = OFF_WUT + (size_t)ISH * H_DIM * 2;
    constexpr size_t OFF_HBUF   = OFF_WDT + (size_t)H_DIM * ISH * 2;
    constexpr size_t OFF_HS     = OFF_HBUF + (size_t)T_TOK * 4 * I_DIM * 2;

    int*    counts = (int*)(ws + OFF_COUNTS);
    __half* zrow   = (__half*)(ws + OFF_ZERO);
    int*    elist  = (int*)(ws + OFF_ELIST);
    float*  ecoef  = (float*)(ws + OFF_ECOEF);
    __half* xq     = (__half*)(ws + OFF_XQ);
    __half* wgt    = (__half*)(ws + OFF_WGT);
    __half* wut    = (__half*)(ws + OFF_WUT);
    __half* wdt    = (__half*)(ws + OFF_WDT);
    __half* h_buf  = (__half*)(ws + OFF_HBUF);
    __half* hs     = (__half*)(ws + OFF_HS);

    hipMemsetAsync(ws, 0, OFF_ZERO + 8192, stream);   // counts + zero row
    k_cvt<<<dim3((T_TOK * H_DIM / 8) / 256), 256, 0, stream>>>(x, xq);
    k_tr<<<dim3(ISH / 32, H_DIM / 32), 256, 0, stream>>>(sgw, wgt, H_DIM, ISH);
    k_tr<<<dim3(ISH / 32, H_DIM / 32), 256, 0, stream>>>(suw, wut, H_DIM, ISH);
    k_tr<<<dim3(H_DIM / 32, ISH / 32), 256, 0, stream>>>(sdw, wdt, ISH, H_DIM);
    k_router<<<dim3(T_TOK), 256, 0, stream>>>(x, gw, counts, elist, ecoef);
    k_gateup<<<dim3(I_DIM / 128, T_TOK / 128, E_NUM), 512, 0, stream>>>(
        xq, gqw, gqz, gsc, uqw, uqz, usc, counts, elist, ecoef, zrow, h_buf);
    k_shared_gu<<<dim3(ISH / 128, T_TOK / 128), 512, 0, stream>>>(xq, wgt, wut, hs);
    k_shared_down<<<dim3(H_DIM / 128, T_TOK / 128), 512, 0, stream>>>(hs, wdt, out);
    k_down<<<dim3(H_DIM / 128, T_TOK / 128, E_NUM), 512, 0, stream>>>(
        h_buf, dqw, dqz, dsc, counts, elist, zrow, out);
}